// Round 7
// baseline (322.854 us; speedup 1.0000x reference)
//
#include <hip/hip_runtime.h>
#include <hip/hip_bf16.h>
#include <cmath>

#define B_    32
#define C_    192
#define H_    56
#define W_    56
#define EPS_  1e-5f
#define SCALE_ 0.20412414523193154f  // 24^-0.5

using bf = __hip_bfloat16;
typedef __attribute__((ext_vector_type(8))) short short8;
typedef __attribute__((ext_vector_type(4))) float f32x4;

// ---------------- K0: qkv_w f32 -> bf16 ----------------
__global__ void k_wconv(const float* __restrict__ qkv_w, bf* __restrict__ wbf) {
    int i = blockIdx.x * 256 + threadIdx.x;
    if (i < 576 * 192) wbf[i] = __float2bfloat16(qkv_w[i]);
}

// ---------------- KA: per-pixel LN0 (ptok), vectorized ----------------
__global__ __launch_bounds__(256) void k_act_ptok(
        const float* __restrict__ x,
        const float* __restrict__ ln0g, const float* __restrict__ ln0b,
        bf* __restrict__ ptok) {
    __shared__ float tile[C_ * 57];
    __shared__ float mv[W_], rv[W_];
    int b = blockIdx.x / H_, h = blockIdx.x % H_;
    const size_t xbase = ((size_t)b * C_ * H_ + h) * W_;

    // load: 192 rows x 14 float4
    for (int i = threadIdx.x; i < C_ * 14; i += 256) {
        int c = i / 14, j = i % 14;
        float4 v = *(const float4*)(x + xbase + (size_t)c * (H_ * W_) + j * 4);
        float* dst = &tile[c * 57 + j * 4];
        dst[0] = v.x; dst[1] = v.y; dst[2] = v.z; dst[3] = v.w;
    }
    __syncthreads();
    if (threadIdx.x < 224) {
        int p = threadIdx.x >> 2, q = threadIdx.x & 3;
        float S = 0.f, Q = 0.f;
        #pragma unroll 8
        for (int j = 0; j < 48; j++) {
            float v = tile[(q * 48 + j) * 57 + p];
            S += v; Q += v * v;
        }
        S += __shfl_xor(S, 1); Q += __shfl_xor(Q, 1);
        S += __shfl_xor(S, 2); Q += __shfl_xor(Q, 2);
        if (q == 0) {
            float mean = S * (1.f / 192.f);
            float var  = Q * (1.f / 192.f) - mean * mean;
            mv[p] = mean; rv[p] = rsqrtf(var + EPS_);
        }
    }
    __syncthreads();
    // write: 24 c-chunks x 56 pixels, bf16x8 stores; lanes stride-1 in p (LDS conflict-free)
    const size_t pbase = (((size_t)b * H_ + h) * W_) * C_;
    for (int it = threadIdx.x; it < 24 * W_; it += 256) {
        int p = it % W_, cb = it / W_;
        float m = mv[p], r = rv[p];
        bf v8[8];
        #pragma unroll
        for (int e = 0; e < 8; e++) {
            int c = cb * 8 + e;
            v8[e] = __float2bfloat16((tile[c * 57 + p] - m) * r * ln0g[c] + ln0b[c]);
        }
        *(uint4*)(ptok + pbase + (size_t)p * C_ + cb * 8) = *(const uint4*)v8;
    }
}

// ---------------- KB: fused BN+GELU + depthwise 7x7 s2 conv ----------------
// mod-4 deinterleaved padded plane Apl[m][62][17]; thread computes an ow-pair
__global__ __launch_bounds__(256) void k_conv(
        const float* __restrict__ x,
        const float* __restrict__ bn_g, const float* __restrict__ bn_b,
        const float* __restrict__ bn_m, const float* __restrict__ bn_v,
        const float* __restrict__ cw, const float* __restrict__ cb,
        float* __restrict__ gbuf) {
    __shared__ float Apl[4][62][17];
    int tid = threadIdx.x;
    int bc = blockIdx.x;               // b*192 + c
    int c = bc % C_;

    float* flat = &Apl[0][0][0];
    for (int i = tid; i < 4 * 62 * 17; i += 256) flat[i] = 0.f;
    __syncthreads();

    float bm = bn_m[c];
    float rs = rsqrtf(bn_v[c] + EPS_) * bn_g[c];
    float bb = bn_b[c];
    const float* xp = x + (size_t)bc * (H_ * W_);
    for (int i = tid; i < 784; i += 256) {
        int row = i / 14, j = i % 14;
        float4 v = *(const float4*)(xp + row * W_ + j * 4);
        #pragma unroll
        for (int e = 0; e < 4; e++) {
            float xv = (e == 0) ? v.x : (e == 1) ? v.y : (e == 2) ? v.z : v.w;
            float xn = (xv - bm) * rs + bb;
            float ge = 0.5f * xn * (1.0f + erff(xn * 0.70710678118654752f));
            int pc = 4 * j + 3 + e;            // padded col
            Apl[pc & 3][row + 3][pc >> 2] = ge;
        }
    }
    __syncthreads();

    float wr[49];
    #pragma unroll
    for (int i = 0; i < 49; i++) wr[i] = cw[c * 49 + i];
    float cbv = cb[c];

    // 392 items: (oh, ow-pair). 9 stride-1 reads/row feed 2 outputs.
    for (int o2 = tid; o2 < 392; o2 += 256) {
        int oh = o2 / 14, g = o2 % 14;
        float acc0 = cbv, acc1 = cbv;
        #pragma unroll
        for (int kh = 0; kh < 7; kh++) {
            int r = 2 * oh + kh;
            float v[9];
            #pragma unroll
            for (int d = 0; d < 9; d++) v[d] = Apl[d & 3][r][g + (d >> 2)];
            #pragma unroll
            for (int kw = 0; kw < 7; kw++) {
                float wv = wr[kh * 7 + kw];
                acc0 += wv * v[kw];
                acc1 += wv * v[kw + 2];
            }
        }
        float2 st = {acc0, acc1};
        *(float2*)(gbuf + (size_t)bc * 784 + oh * 28 + 2 * g) = st;
    }
}

// ---------------- KC: LN0 over channels of g -> gtok (bf16), vectorized ----------------
__global__ __launch_bounds__(256) void k_gtok(
        const float* __restrict__ gbuf,
        const float* __restrict__ ln0g, const float* __restrict__ ln0b,
        bf* __restrict__ gtok) {
    __shared__ float tile[C_ * 29];
    __shared__ float mv[28], rv[28];
    int b = blockIdx.x / 28, oh = blockIdx.x % 28;
    size_t gbase = ((size_t)b * C_ * 784) + (size_t)oh * 28;
    for (int i = threadIdx.x; i < C_ * 7; i += 256) {
        int c = i / 7, j = i % 7;
        float4 v = *(const float4*)(gbuf + gbase + (size_t)c * 784 + j * 4);
        float* dst = &tile[c * 29 + j * 4];
        dst[0] = v.x; dst[1] = v.y; dst[2] = v.z; dst[3] = v.w;
    }
    __syncthreads();
    if (threadIdx.x < 112) {
        int p = threadIdx.x >> 2, q = threadIdx.x & 3;
        float S = 0.f, Q = 0.f;
        #pragma unroll 8
        for (int j = 0; j < 48; j++) {
            float v = tile[(q * 48 + j) * 29 + p];
            S += v; Q += v * v;
        }
        S += __shfl_xor(S, 1); Q += __shfl_xor(Q, 1);
        S += __shfl_xor(S, 2); Q += __shfl_xor(Q, 2);
        if (q == 0) {
            float mean = S * (1.f / 192.f);
            float var  = Q * (1.f / 192.f) - mean * mean;
            mv[p] = mean; rv[p] = rsqrtf(var + EPS_);
        }
    }
    __syncthreads();
    size_t tbase = ((size_t)b * 784 + (size_t)oh * 28) * C_;
    for (int it = threadIdx.x; it < 24 * 28; it += 256) {
        int p = it % 28, cb = it / 28;
        float m = mv[p], r = rv[p];
        bf v8[8];
        #pragma unroll
        for (int e = 0; e < 8; e++) {
            int c = cb * 8 + e;
            v8[e] = __float2bfloat16((tile[c * 29 + p] - m) * r * ln0g[c] + ln0b[c]);
        }
        *(uint4*)(gtok + tbase + (size_t)p * C_ + cb * 8) = *(const uint4*)v8;
    }
}

// ---------------- K_GEMM: [M,192] x [192, 576-COLOFS] -> bf16, bias folded ----------------
// WINDOWED: remap output rows (pixels) to window-grouped kvp2[bw][4][384]
template<int COLOFS, bool WINDOWED>
__global__ __launch_bounds__(256) void k_gemm(
        const bf* __restrict__ A, const bf* __restrict__ wbf,
        const float* __restrict__ qkv_b, bf* __restrict__ out) {
    __shared__ unsigned char Asm_[128 * 384];
    int tid = threadIdx.x;
    size_t r0 = (size_t)blockIdx.x * 128;

    for (int i = tid; i < 128 * 24; i += 256) {
        int row = i / 24, j = i % 24;
        uint4 v = *(const uint4*)((const unsigned char*)(A + (r0 + row) * C_) + j * 16);
        *(uint4*)(Asm_ + row * 384 + ((j * 16) ^ ((row & 7) << 4))) = v;
    }
    __syncthreads();

    int wid = tid >> 6, lane = tid & 63, lo = lane & 15, hi = lane >> 4;
    int xorv = (lo & 7) << 4;
    constexpr int NT = (576 - COLOFS) / 16;

    // per-lane destination row offsets (static-indexed; computed once)
    int dstb[8][4];
    #pragma unroll
    for (int m = 0; m < 8; m++) {
        #pragma unroll
        for (int r = 0; r < 4; r++) {
            int row = m * 16 + hi * 4 + r;
            if (WINDOWED) {
                int p = (int)r0 + row;
                int b = p / 3136, rem = p - b * 3136;
                int h = rem / 56, w = rem - h * 56;
                int bw = b * 784 + (h >> 1) * 28 + (w >> 1);
                int t = (h & 1) * 2 + (w & 1);
                dstb[m][r] = (bw * 4 + t) * 384;
            } else {
                dstb[m][r] = ((int)r0 + row) * (576 - COLOFS);
            }
        }
    }

    for (int nt = wid; nt < NT; nt += 4) {
        int col = COLOFS + nt * 16 + lo;
        float bias = qkv_b[col];
        f32x4 acc[8];
        #pragma unroll
        for (int m = 0; m < 8; m++) acc[m] = {bias, bias, bias, bias};
        const unsigned char* bbase = (const unsigned char*)wbf + (size_t)col * 384 + hi * 16;
        #pragma unroll
        for (int ks = 0; ks < 6; ks++) {
            short8 bfrag = *(const short8*)(bbase + ks * 64);
            int kb = (ks * 64 + hi * 16) ^ xorv;
            #pragma unroll
            for (int m = 0; m < 8; m++) {
                short8 a = *(const short8*)(Asm_ + (m * 16 + lo) * 384 + kb);
                acc[m] = __builtin_amdgcn_mfma_f32_16x16x32_bf16(a, bfrag, acc[m], 0, 0, 0);
            }
        }
        int cofs = col - COLOFS;
        #pragma unroll
        for (int m = 0; m < 8; m++) {
            #pragma unroll
            for (int r = 0; r < 4; r++)
                out[(size_t)dstb[m][r] + cofs] = __float2bfloat16(acc[m][r]);
        }
    }
}

// ---------------- K_ATT2: per (window, head) attention + LN1 ----------------
// kvp2 [bw][4][384] (k|v per local token), qkvg [bw][576]; out f32 [bw][192]
__global__ __launch_bounds__(256) void k_att2(
        const bf* __restrict__ kvp2, const bf* __restrict__ qkvg,
        const float* __restrict__ ln1g, const float* __restrict__ ln1b,
        float* __restrict__ out) {
    int tg = blockIdx.x * 256 + threadIdx.x;   // 784 blocks
    int bw = tg >> 3, hh = tg & 7;

    const bf* qb = qkvg + (size_t)bw * 576 + hh * 24;
    float q[24];
    #pragma unroll
    for (int j = 0; j < 3; j++) {
        short8 v = *(const short8*)(qb + j * 8);
        #pragma unroll
        for (int e = 0; e < 8; e++)
            q[j * 8 + e] = __uint_as_float(((unsigned)(unsigned short)v[e]) << 16);
    }

    float s[5];
    {   // guide k
        float a = 0.f;
        #pragma unroll
        for (int j = 0; j < 3; j++) {
            short8 v = *(const short8*)(qb + 192 + j * 8);
            #pragma unroll
            for (int e = 0; e < 8; e++)
                a += q[j * 8 + e] * __uint_as_float(((unsigned)(unsigned short)v[e]) << 16);
        }
        s[0] = a * SCALE_;
    }
    #pragma unroll
    for (int t = 0; t < 4; t++) {
        const bf* kb = kvp2 + ((size_t)bw * 4 + t) * 384 + hh * 24;
        float a = 0.f;
        #pragma unroll
        for (int j = 0; j < 3; j++) {
            short8 v = *(const short8*)(kb + j * 8);
            #pragma unroll
            for (int e = 0; e < 8; e++)
                a += q[j * 8 + e] * __uint_as_float(((unsigned)(unsigned short)v[e]) << 16);
        }
        s[t + 1] = a * SCALE_;
    }
    float mx = fmaxf(fmaxf(fmaxf(s[0], s[1]), fmaxf(s[2], s[3])), s[4]);
    float sum = 0.f;
    #pragma unroll
    for (int t = 0; t < 5; t++) { s[t] = expf(s[t] - mx); sum += s[t]; }
    float inv = 1.f / sum;
    #pragma unroll
    for (int t = 0; t < 5; t++) s[t] *= inv;

    float o[24];
    #pragma unroll
    for (int d = 0; d < 24; d++) o[d] = 0.f;
    {   // guide v
        #pragma unroll
        for (int j = 0; j < 3; j++) {
            short8 v = *(const short8*)(qb + 384 + j * 8);
            #pragma unroll
            for (int e = 0; e < 8; e++)
                o[j * 8 + e] += s[0] * __uint_as_float(((unsigned)(unsigned short)v[e]) << 16);
        }
    }
    #pragma unroll
    for (int t = 0; t < 4; t++) {
        const bf* vb = kvp2 + ((size_t)bw * 4 + t) * 384 + 192 + hh * 24;
        #pragma unroll
        for (int j = 0; j < 3; j++) {
            short8 v = *(const short8*)(vb + j * 8);
            #pragma unroll
            for (int e = 0; e < 8; e++)
                o[j * 8 + e] += s[t + 1] * __uint_as_float(((unsigned)(unsigned short)v[e]) << 16);
        }
    }

    float S = 0.f, Q = 0.f;
    #pragma unroll
    for (int d = 0; d < 24; d++) { S += o[d]; Q += o[d] * o[d]; }
    S += __shfl_xor(S, 1); Q += __shfl_xor(Q, 1);
    S += __shfl_xor(S, 2); Q += __shfl_xor(Q, 2);
    S += __shfl_xor(S, 4); Q += __shfl_xor(Q, 4);
    float mean = S * (1.f / 192.f);
    float var  = Q * (1.f / 192.f) - mean * mean;
    float rstd = rsqrtf(var + EPS_);
    float* ob = out + (size_t)bw * 192 + hh * 24;
    #pragma unroll
    for (int d = 0; d < 24; d++)
        ob[d] = (o[d] - mean) * rstd * ln1g[hh * 24 + d] + ln1b[hh * 24 + d];
}

// ---------------- launch ----------------
extern "C" void kernel_launch(void* const* d_in, const int* in_sizes, int n_in,
                              void* d_out, int out_size, void* d_ws, size_t ws_size,
                              hipStream_t stream) {
    const float* x       = (const float*)d_in[0];
    const float* bn_g    = (const float*)d_in[1];
    const float* bn_b    = (const float*)d_in[2];
    const float* bn_m    = (const float*)d_in[3];
    const float* bn_v    = (const float*)d_in[4];
    const float* conv_w  = (const float*)d_in[5];
    const float* conv_b  = (const float*)d_in[6];
    const float* qkv_w   = (const float*)d_in[7];
    const float* qkv_b   = (const float*)d_in[8];
    const float* ln0g    = (const float*)d_in[9];
    const float* ln0b    = (const float*)d_in[10];
    const float* ln1g    = (const float*)d_in[11];
    const float* ln1b    = (const float*)d_in[12];

    char* ws = (char*)d_ws;
    // layout: ptok 0 | gtok 38,535,168 | wbf 48,168,960 | kvp2 48,390,144 |
    //         qkvg 125,460,480 (gbuf overlaid; dead before qkvg written) | end 154,361,856
    bf*    ptok = (bf*)(ws);
    bf*    gtok = (bf*)(ws + 38535168);
    bf*    wbf  = (bf*)(ws + 48168960);
    bf*    kvp2 = (bf*)(ws + 48390144);
    bf*    qkvg = (bf*)(ws + 125460480);
    float* gbuf = (float*)(ws + 125460480);        // overlaid with qkvg

    k_wconv   <<<dim3(432),   dim3(256), 0, stream>>>(qkv_w, wbf);
    k_conv    <<<dim3(B_*C_), dim3(256), 0, stream>>>(x, bn_g, bn_b, bn_m, bn_v,
                                                      conv_w, conv_b, gbuf);
    k_act_ptok<<<dim3(B_*H_), dim3(256), 0, stream>>>(x, ln0g, ln0b, ptok);
    k_gtok    <<<dim3(B_*28), dim3(256), 0, stream>>>(gbuf, ln0g, ln0b, gtok);
    k_gemm<192, true> <<<dim3(784), dim3(256), 0, stream>>>(ptok, wbf, qkv_b, kvp2);
    k_gemm<0, false>  <<<dim3(196), dim3(256), 0, stream>>>(gtok, wbf, qkv_b, qkvg);
    k_att2    <<<dim3(784),  dim3(256), 0, stream>>>(kvp2, qkvg, ln1g, ln1b,
                                                     (float*)d_out);
}

// Round 14
// 292.966 us; speedup vs baseline: 1.1020x; 1.1020x over previous
//
#include <hip/hip_runtime.h>
#include <hip/hip_bf16.h>
#include <cmath>

#define B_    32
#define C_    192
#define H_    56
#define W_    56
#define EPS_  1e-5f
#define SCALE_ 0.20412414523193154f  // 24^-0.5

using bf = __hip_bfloat16;
typedef __attribute__((ext_vector_type(8))) short short8;
typedef __attribute__((ext_vector_type(4))) float f32x4;

// ---------------- K_WPREP: fold ln0 gamma/beta into W and bias ----------------
// W'[j][c] = W[j][c]*ln0g[c] (bf16); bias2[j] = qkv_b[j] + sum_c W[j][c]*ln0b[c]
__global__ __launch_bounds__(192) void k_wprep(
        const float* __restrict__ qkv_w, const float* __restrict__ qkv_b,
        const float* __restrict__ ln0g, const float* __restrict__ ln0b,
        bf* __restrict__ wbf, float* __restrict__ bias2) {
    int j = blockIdx.x * 192 + threadIdx.x;          // 0..575
    const float* wr = qkv_w + (size_t)j * 192;
    bf* wo = wbf + (size_t)j * 192;
    float acc = 0.f;
    for (int c = 0; c < 192; c++) {
        float w = wr[c];
        acc += w * ln0b[c];
        wo[c] = __float2bfloat16(w * ln0g[c]);
    }
    bias2[j] = qkv_b[j] + acc;
}

// ---------------- KB: fused BN+GELU + depthwise 7x7 s2 conv (proven r7) ----------------
__global__ __launch_bounds__(256) void k_conv(
        const float* __restrict__ x,
        const float* __restrict__ bn_g, const float* __restrict__ bn_b,
        const float* __restrict__ bn_m, const float* __restrict__ bn_v,
        const float* __restrict__ cw, const float* __restrict__ cb,
        float* __restrict__ gbuf) {
    __shared__ float Apl[4][62][17];
    int tid = threadIdx.x;
    int bc = blockIdx.x;               // b*192 + c
    int c = bc % C_;

    float* flat = &Apl[0][0][0];
    for (int i = tid; i < 4 * 62 * 17; i += 256) flat[i] = 0.f;
    __syncthreads();

    float bm = bn_m[c];
    float rs = rsqrtf(bn_v[c] + EPS_) * bn_g[c];
    float bb = bn_b[c];
    const float* xp = x + (size_t)bc * (H_ * W_);
    for (int i = tid; i < 784; i += 256) {
        int row = i / 14, j = i % 14;
        float4 v = *(const float4*)(xp + row * W_ + j * 4);
        #pragma unroll
        for (int e = 0; e < 4; e++) {
            float xv = (e == 0) ? v.x : (e == 1) ? v.y : (e == 2) ? v.z : v.w;
            float xn = (xv - bm) * rs + bb;
            float ge = 0.5f * xn * (1.0f + erff(xn * 0.70710678118654752f));
            int pc = 4 * j + 3 + e;            // padded col
            Apl[pc & 3][row + 3][pc >> 2] = ge;
        }
    }
    __syncthreads();

    float wr[49];
    #pragma unroll
    for (int i = 0; i < 49; i++) wr[i] = cw[c * 49 + i];
    float cbv = cb[c];

    for (int o2 = tid; o2 < 392; o2 += 256) {
        int oh = o2 / 14, g = o2 % 14;
        float acc0 = cbv, acc1 = cbv;
        #pragma unroll
        for (int kh = 0; kh < 7; kh++) {
            int r = 2 * oh + kh;
            float v[9];
            #pragma unroll
            for (int d = 0; d < 9; d++) v[d] = Apl[d & 3][r][g + (d >> 2)];
            #pragma unroll
            for (int kw = 0; kw < 7; kw++) {
                float wv = wr[kh * 7 + kw];
                acc0 += wv * v[kw];
                acc1 += wv * v[kw + 2];
            }
        }
        float2 st = {acc0, acc1};
        *(float2*)(gbuf + (size_t)bc * 784 + oh * 28 + 2 * g) = st;
    }
}

// ---------------- K_PGEMM: fused per-pixel LN0 + [56,192]x[192,384] -> kvp ----------------
// one block per (b,h) strip; A = (x-mean)*rstd in swizzled LDS bf16 [64][192] (8 pad rows)
__global__ __launch_bounds__(256) void k_pgemm(
        const float* __restrict__ x, const bf* __restrict__ wbf,
        const float* __restrict__ bias2, bf* __restrict__ kvp) {
    __shared__ unsigned char Asm_[64 * 384];
    __shared__ float mv[56], rv[56];
    int tid = threadIdx.x;
    int b = blockIdx.x / H_, h = blockIdx.x % H_;
    const float* xp = x + ((size_t)b * C_ * H_ + h) * W_;   // + c*3136 + w

    // zero pad rows 56..63 (swizzle is row-local -> plain zero fill suffices)
    for (int i = tid; i < 8 * 24; i += 256) {
        uint4 z = {0u, 0u, 0u, 0u};
        *(uint4*)(Asm_ + (56 + i / 24) * 384 + (i % 24) * 16) = z;
    }
    // P1: load x [c][w] coalesced, write bf16 transposed A[w][c] (swizzled)
    for (int i = tid; i < C_ * 14; i += 256) {
        int c = i / 14, j4 = i % 14;
        float4 v = *(const float4*)(xp + (size_t)c * (H_ * W_) + j4 * 4);
        #pragma unroll
        for (int e = 0; e < 4; e++) {
            int w = j4 * 4 + e;
            float xv = (e == 0) ? v.x : (e == 1) ? v.y : (e == 2) ? v.z : v.w;
            *(bf*)(Asm_ + w * 384 + ((2 * c) ^ ((w & 7) << 4))) = __float2bfloat16(xv);
        }
    }
    __syncthreads();
    // P2a: per-pixel stats (4 threads/pixel)
    if (tid < 224) {
        int w = tid >> 2, q = tid & 3;
        float S = 0.f, Q = 0.f;
        #pragma unroll
        for (int jj = 0; jj < 6; jj++) {
            int j = q * 6 + jj;
            short8 a = *(const short8*)(Asm_ + w * 384 + ((j * 16) ^ ((w & 7) << 4)));
            #pragma unroll
            for (int e = 0; e < 8; e++) {
                float v = __uint_as_float(((unsigned)(unsigned short)a[e]) << 16);
                S += v; Q += v * v;
            }
        }
        S += __shfl_xor(S, 1); Q += __shfl_xor(Q, 1);
        S += __shfl_xor(S, 2); Q += __shfl_xor(Q, 2);
        if (q == 0) {
            float mean = S * (1.f / 192.f);
            float var  = Q * (1.f / 192.f) - mean * mean;
            mv[w] = mean; rv[w] = rsqrtf(var + EPS_);
        }
    }
    __syncthreads();
    // P2b: normalize rows in place
    for (int i = tid; i < 56 * 24; i += 256) {
        int w = i / 24, j = i % 24;
        unsigned char* p = Asm_ + w * 384 + ((j * 16) ^ ((w & 7) << 4));
        short8 a = *(const short8*)p;
        float m = mv[w], r = rv[w];
        short8 o;
        #pragma unroll
        for (int e = 0; e < 8; e++) {
            float v = __uint_as_float(((unsigned)(unsigned short)a[e]) << 16);
            bf bv = __float2bfloat16((v - m) * r);
            o[e] = *(short*)&bv;
        }
        *(short8*)p = o;
    }
    __syncthreads();
    // P3: GEMM rows 0..63 x cols 192..575 (k|v)
    int wid = tid >> 6, lane = tid & 63, lo = lane & 15, hi = lane >> 4;
    int xorv = (lo & 7) << 4;
    int pix0 = (b * H_ + h) * W_;
    for (int nn = 0; nn < 6; nn++) {
        int nt = nn * 4 + wid;
        int col = 192 + nt * 16 + lo;
        float bias = bias2[col];
        f32x4 acc[4];
        #pragma unroll
        for (int m = 0; m < 4; m++) acc[m] = {bias, bias, bias, bias};
        const unsigned char* bbase = (const unsigned char*)wbf + (size_t)col * 384 + hi * 16;
        #pragma unroll
        for (int ks = 0; ks < 6; ks++) {
            short8 bfrag = *(const short8*)(bbase + ks * 64);
            int kb = (ks * 64 + hi * 16) ^ xorv;
            #pragma unroll
            for (int m = 0; m < 4; m++) {
                short8 a = *(const short8*)(Asm_ + (m * 16 + lo) * 384 + kb);
                acc[m] = __builtin_amdgcn_mfma_f32_16x16x32_bf16(a, bfrag, acc[m], 0, 0, 0);
            }
        }
        int cofs = col - 192;
        #pragma unroll
        for (int m = 0; m < 4; m++) {
            #pragma unroll
            for (int r = 0; r < 4; r++) {
                int row = m * 16 + hi * 4 + r;
                if (row < 56)
                    kvp[(size_t)(pix0 + row) * 384 + cofs] = __float2bfloat16(acc[m][r]);
            }
        }
    }
}

// ---------------- K_GGEMM: fused guide LN0 + [28,192]x[192,576] -> qkvg ----------------
// one block per (b,oh) strip; A [32][192] (4 pad rows)
__global__ __launch_bounds__(256) void k_ggemm(
        const float* __restrict__ gbuf, const bf* __restrict__ wbf,
        const float* __restrict__ bias2, bf* __restrict__ qkvg) {
    __shared__ unsigned char Asm_[32 * 384];
    __shared__ float mv[28], rv[28];
    int tid = threadIdx.x;
    int b = blockIdx.x / 28, oh = blockIdx.x % 28;
    const float* gp = gbuf + (size_t)b * C_ * 784 + (size_t)oh * 28;  // + c*784 + ow

    for (int i = tid; i < 4 * 24; i += 256) {
        uint4 z = {0u, 0u, 0u, 0u};
        *(uint4*)(Asm_ + (28 + i / 24) * 384 + (i % 24) * 16) = z;
    }
    for (int i = tid; i < C_ * 7; i += 256) {
        int c = i / 7, j4 = i % 7;
        float4 v = *(const float4*)(gp + (size_t)c * 784 + j4 * 4);
        #pragma unroll
        for (int e = 0; e < 4; e++) {
            int w = j4 * 4 + e;
            float xv = (e == 0) ? v.x : (e == 1) ? v.y : (e == 2) ? v.z : v.w;
            *(bf*)(Asm_ + w * 384 + ((2 * c) ^ ((w & 7) << 4))) = __float2bfloat16(xv);
        }
    }
    __syncthreads();
    if (tid < 112) {
        int w = tid >> 2, q = tid & 3;
        float S = 0.f, Q = 0.f;
        #pragma unroll
        for (int jj = 0; jj < 6; jj++) {
            int j = q * 6 + jj;
            short8 a = *(const short8*)(Asm_ + w * 384 + ((j * 16) ^ ((w & 7) << 4)));
            #pragma unroll
            for (int e = 0; e < 8; e++) {
                float v = __uint_as_float(((unsigned)(unsigned short)a[e]) << 16);
                S += v; Q += v * v;
            }
        }
        S += __shfl_xor(S, 1); Q += __shfl_xor(Q, 1);
        S += __shfl_xor(S, 2); Q += __shfl_xor(Q, 2);
        if (q == 0) {
            float mean = S * (1.f / 192.f);
            float var  = Q * (1.f / 192.f) - mean * mean;
            mv[w] = mean; rv[w] = rsqrtf(var + EPS_);
        }
    }
    __syncthreads();
    for (int i = tid; i < 28 * 24; i += 256) {
        int w = i / 24, j = i % 24;
        unsigned char* p = Asm_ + w * 384 + ((j * 16) ^ ((w & 7) << 4));
        short8 a = *(const short8*)p;
        float m = mv[w], r = rv[w];
        short8 o;
        #pragma unroll
        for (int e = 0; e < 8; e++) {
            float v = __uint_as_float(((unsigned)(unsigned short)a[e]) << 16);
            bf bv = __float2bfloat16((v - m) * r);
            o[e] = *(short*)&bv;
        }
        *(short8*)p = o;
    }
    __syncthreads();
    int wid = tid >> 6, lane = tid & 63, lo = lane & 15, hi = lane >> 4;
    int xorv = (lo & 7) << 4;
    int gpix0 = b * 784 + oh * 28;
    for (int nn = 0; nn < 9; nn++) {
        int nt = nn * 4 + wid;
        int col = nt * 16 + lo;
        float bias = bias2[col];
        f32x4 acc[2];
        #pragma unroll
        for (int m = 0; m < 2; m++) acc[m] = {bias, bias, bias, bias};
        const unsigned char* bbase = (const unsigned char*)wbf + (size_t)col * 384 + hi * 16;
        #pragma unroll
        for (int ks = 0; ks < 6; ks++) {
            short8 bfrag = *(const short8*)(bbase + ks * 64);
            int kb = (ks * 64 + hi * 16) ^ xorv;
            #pragma unroll
            for (int m = 0; m < 2; m++) {
                short8 a = *(const short8*)(Asm_ + (m * 16 + lo) * 384 + kb);
                acc[m] = __builtin_amdgcn_mfma_f32_16x16x32_bf16(a, bfrag, acc[m], 0, 0, 0);
            }
        }
        #pragma unroll
        for (int m = 0; m < 2; m++) {
            #pragma unroll
            for (int r = 0; r < 4; r++) {
                int row = m * 16 + hi * 4 + r;
                if (row < 28)
                    qkvg[(size_t)(gpix0 + row) * 576 + col] = __float2bfloat16(acc[m][r]);
            }
        }
    }
}

// ---------------- K_ATT2: per (window, head) attention + LN1 (r5-proven) ----------------
// kvp [100352][384] (k|v), qkvg [25088][576] (q|k|v); out f32 [25088][192]
__global__ __launch_bounds__(256) void k_att2(
        const bf* __restrict__ kvp, const bf* __restrict__ qkvg,
        const float* __restrict__ ln1g, const float* __restrict__ ln1b,
        float* __restrict__ out) {
    int tg = blockIdx.x * 256 + threadIdx.x;   // 784 blocks
    int bw = tg >> 3, hh = tg & 7;
    int b = bw / 784, rr = bw % 784;
    int oh = rr / 28, ow = rr % 28;

    const bf* qb = qkvg + (size_t)bw * 576 + hh * 24;
    float q[24];
    #pragma unroll
    for (int j = 0; j < 3; j++) {
        short8 v = *(const short8*)(qb + j * 8);
        #pragma unroll
        for (int e = 0; e < 8; e++)
            q[j * 8 + e] = __uint_as_float(((unsigned)(unsigned short)v[e]) << 16);
    }
    size_t pr[4];
    #pragma unroll
    for (int t = 0; t < 4; t++) {
        int h = 2 * oh + (t >> 1), w = 2 * ow + (t & 1);
        pr[t] = ((size_t)b * H_ + h) * W_ + w;
    }

    float s[5];
    {   // guide k
        float a = 0.f;
        #pragma unroll
        for (int j = 0; j < 3; j++) {
            short8 v = *(const short8*)(qb + 192 + j * 8);
            #pragma unroll
            for (int e = 0; e < 8; e++)
                a += q[j * 8 + e] * __uint_as_float(((unsigned)(unsigned short)v[e]) << 16);
        }
        s[0] = a * SCALE_;
    }
    #pragma unroll
    for (int t = 0; t < 4; t++) {
        const bf* kb = kvp + pr[t] * 384 + hh * 24;
        float a = 0.f;
        #pragma unroll
        for (int j = 0; j < 3; j++) {
            short8 v = *(const short8*)(kb + j * 8);
            #pragma unroll
            for (int e = 0; e < 8; e++)
                a += q[j * 8 + e] * __uint_as_float(((unsigned)(unsigned short)v[e]) << 16);
        }
        s[t + 1] = a * SCALE_;
    }
    float mx = fmaxf(fmaxf(fmaxf(s[0], s[1]), fmaxf(s[2], s[3])), s[4]);
    float sum = 0.f;
    #pragma unroll
    for (int t = 0; t < 5; t++) { s[t] = expf(s[t] - mx); sum += s[t]; }
    float inv = 1.f / sum;
    #pragma unroll
    for (int t = 0; t < 5; t++) s[t] *= inv;

    float o[24];
    #pragma unroll
    for (int d = 0; d < 24; d++) o[d] = 0.f;
    {   // guide v
        #pragma unroll
        for (int j = 0; j < 3; j++) {
            short8 v = *(const short8*)(qb + 384 + j * 8);
            #pragma unroll
            for (int e = 0; e < 8; e++)
                o[j * 8 + e] += s[0] * __uint_as_float(((unsigned)(unsigned short)v[e]) << 16);
        }
    }
    #pragma unroll
    for (int t = 0; t < 4; t++) {
        const bf* vb = kvp + pr[t] * 384 + 192 + hh * 24;
        #pragma unroll
        for (int j = 0; j < 3; j++) {
            short8 v = *(const short8*)(vb + j * 8);
            #pragma unroll
            for (int e = 0; e < 8; e++)
                o[j * 8 + e] += s[t + 1] * __uint_as_float(((unsigned)(unsigned short)v[e]) << 16);
        }
    }

    float S = 0.f, Q = 0.f;
    #pragma unroll
    for (int d = 0; d < 24; d++) { S += o[d]; Q += o[d] * o[d]; }
    S += __shfl_xor(S, 1); Q += __shfl_xor(Q, 1);
    S += __shfl_xor(S, 2); Q += __shfl_xor(Q, 2);
    S += __shfl_xor(S, 4); Q += __shfl_xor(Q, 4);
    float mean = S * (1.f / 192.f);
    float var  = Q * (1.f / 192.f) - mean * mean;
    float rstd = rsqrtf(var + EPS_);
    float* ob = out + (size_t)bw * 192 + hh * 24;
    #pragma unroll
    for (int d = 0; d < 24; d++)
        ob[d] = (o[d] - mean) * rstd * ln1g[hh * 24 + d] + ln1b[hh * 24 + d];
}

// ---------------- launch ----------------
extern "C" void kernel_launch(void* const* d_in, const int* in_sizes, int n_in,
                              void* d_out, int out_size, void* d_ws, size_t ws_size,
                              hipStream_t stream) {
    const float* x       = (const float*)d_in[0];
    const float* bn_g    = (const float*)d_in[1];
    const float* bn_b    = (const float*)d_in[2];
    const float* bn_m    = (const float*)d_in[3];
    const float* bn_v    = (const float*)d_in[4];
    const float* conv_w  = (const float*)d_in[5];
    const float* conv_b  = (const float*)d_in[6];
    const float* qkv_w   = (const float*)d_in[7];
    const float* qkv_b   = (const float*)d_in[8];
    const float* ln0g    = (const float*)d_in[9];
    const float* ln0b    = (const float*)d_in[10];
    const float* ln1g    = (const float*)d_in[11];
    const float* ln1b    = (const float*)d_in[12];

    char* ws = (char*)d_ws;
    // layout (bytes): wbf 0..221184 | bias2 ..223488 | gbuf ..19491072(+19267584)
    //                 kvp @19491072 (+77070336) | qkvg @96561408 (+28901376) = 125462784
    bf*    wbf   = (bf*)(ws);
    float* bias2 = (float*)(ws + 221184);
    float* gbuf  = (float*)(ws + 223488);
    bf*    kvp   = (bf*)(ws + 19491072);
    bf*    qkvg  = (bf*)(ws + 96561408);

    k_wprep <<<dim3(3),     dim3(192), 0, stream>>>(qkv_w, qkv_b, ln0g, ln0b, wbf, bias2);
    k_conv  <<<dim3(B_*C_), dim3(256), 0, stream>>>(x, bn_g, bn_b, bn_m, bn_v,
                                                    conv_w, conv_b, gbuf);
    k_pgemm <<<dim3(B_*H_), dim3(256), 0, stream>>>(x, wbf, bias2, kvp);
    k_ggemm <<<dim3(B_*28), dim3(256), 0, stream>>>(gbuf, wbf, bias2, qkvg);
    k_att2  <<<dim3(784),   dim3(256), 0, stream>>>(kvp, qkvg, ln1g, ln1b,
                                                    (float*)d_out);
}